// Round 1
// baseline (7884.243 us; speedup 1.0000x reference)
//
#include <hip/hip_runtime.h>
#include <stdint.h>

// Problem: T=1024 steps, B=32, D=1024, fp32 io.
//   Phase 1 (parallel): P[t,b, 0:3072] = x[t,b,:] @ [W_alpha;W_beta;W_x]^T  (bf16 MFMA GEMM)
//   Phase 2 (sequential): persistent-RNN kernel, 128 WGs = 2 batch-groups x 64 dim-slices,
//     recurrent weights live in VGPRs as MFMA B-fragments, 64-WG group barrier per step
//     via per-step agent-scope atomic counters (cross-XCD safe).

#define TT 1024
#define BB 32
#define DD 1024
#define GM (TT * BB)   // 32768
#define GN 3072
#define GK 1024

typedef __attribute__((ext_vector_type(8))) __bf16 bf16x8;
typedef __attribute__((ext_vector_type(8))) unsigned short us8;
typedef __attribute__((ext_vector_type(4))) float f32x4;
typedef unsigned short ushort_t;

__device__ __forceinline__ unsigned short f2bf(float f) {
    unsigned u = __builtin_bit_cast(unsigned, f);
    return (unsigned short)((u + 0x8000u) >> 16);  // round-half-up; inputs are finite
}
__device__ __forceinline__ float bf2f(unsigned short h) {
    unsigned u = ((unsigned)h) << 16;
    return __builtin_bit_cast(float, u);
}

// ---------------------------------------------------------------- cvt fp32->bf16
__global__ __launch_bounds__(256) void cvt_f32_bf16(const float4* __restrict__ src,
                                                    ushort4* __restrict__ dst, int n4) {
    int i = blockIdx.x * 256 + threadIdx.x;
    int stride = gridDim.x * 256;
    for (; i < n4; i += stride) {
        float4 v = src[i];
        ushort4 o;
        o.x = f2bf(v.x); o.y = f2bf(v.y); o.z = f2bf(v.z); o.w = f2bf(v.w);
        dst[i] = o;
    }
}

// ---------------------------------------------------------------- GEMM: P = Xbf @ Wcat^T
// 128x128 tile, BK=64, 4 waves in 2x2, XOR-swizzled LDS (16B chunk ^ (row&7)) -> 2-way (free).
#define SUPER 16
__global__ __launch_bounds__(256) void gemm_xproj(const ushort_t* __restrict__ A,   // 32768x1024 bf16
                                                  const ushort_t* __restrict__ Bw,  // 3072x1024 bf16
                                                  ushort_t* __restrict__ P) {       // 32768x3072 bf16
    __shared__ ushort_t As[128 * 64];
    __shared__ ushort_t Bs[128 * 64];

    int bid = blockIdx.x;
    int st = bid / (SUPER * 24);
    int r  = bid % (SUPER * 24);
    int tm = st * SUPER + (r & (SUPER - 1));   // supertile order: 16 M-tiles share A in L2/LLC
    int tn = r / SUPER;

    int tid = threadIdx.x;
    int lane = tid & 63, wv = tid >> 6;
    int wm = wv >> 1, wn = wv & 1;
    int l15 = lane & 15, q = lane >> 4;

    f32x4 acc[4][4];
#pragma unroll
    for (int mi = 0; mi < 4; mi++)
#pragma unroll
        for (int ni = 0; ni < 4; ni++) acc[mi][ni] = (f32x4){0.f, 0.f, 0.f, 0.f};

    const ushort_t* Abase = A + (size_t)(tm * 128) * GK;
    const ushort_t* Bbase = Bw + (size_t)(tn * 128) * GK;
    int c8 = tid & 7, rr = tid >> 3;  // rr: 0..31

    for (int kit = 0; kit < 16; kit++) {
        int k0 = kit * 64;
        if (kit) __syncthreads();
#pragma unroll
        for (int p = 0; p < 4; p++) {
            int row = p * 32 + rr;
            int sw = c8 ^ (row & 7);
            uint4 va = *(const uint4*)(Abase + (size_t)row * GK + k0 + c8 * 8);
            *(uint4*)&As[row * 64 + sw * 8] = va;
            uint4 vb = *(const uint4*)(Bbase + (size_t)row * GK + k0 + c8 * 8);
            *(uint4*)&Bs[row * 64 + sw * 8] = vb;
        }
        __syncthreads();
#pragma unroll
        for (int ks = 0; ks < 2; ks++) {
            bf16x8 af[4], bfr[4];
#pragma unroll
            for (int mi = 0; mi < 4; mi++) {
                int rl = wm * 64 + mi * 16 + l15;
                int sw = (ks * 4 + q) ^ (rl & 7);
                af[mi] = *(const bf16x8*)&As[rl * 64 + sw * 8];
            }
#pragma unroll
            for (int ni = 0; ni < 4; ni++) {
                int rl = wn * 64 + ni * 16 + l15;
                int sw = (ks * 4 + q) ^ (rl & 7);
                bfr[ni] = *(const bf16x8*)&Bs[rl * 64 + sw * 8];
            }
#pragma unroll
            for (int mi = 0; mi < 4; mi++)
#pragma unroll
                for (int ni = 0; ni < 4; ni++)
                    acc[mi][ni] = __builtin_amdgcn_mfma_f32_16x16x32_bf16(af[mi], bfr[ni], acc[mi][ni], 0, 0, 0);
        }
    }
    // epilogue: C/D layout col=lane&15, row=(lane>>4)*4+reg  [verified m89/m91]
#pragma unroll
    for (int mi = 0; mi < 4; mi++)
#pragma unroll
        for (int ni = 0; ni < 4; ni++) {
            int n = tn * 128 + wn * 64 + ni * 16 + l15;
#pragma unroll
            for (int i = 0; i < 4; i++) {
                int m = tm * 128 + wm * 64 + mi * 16 + q * 4 + i;
                P[(size_t)m * GN + n] = f2bf(acc[mi][ni][i]);
            }
        }
}

// ---------------------------------------------------------------- persistent RNN scan
// 128 WGs: bg = blockIdx>>6 (16 batches), slice = blockIdx&63 (16 dims).
// Weights as B-frags in registers: wf[mat][ks], wave wv covers k in [wv*256, wv*256+256).
__global__ __launch_bounds__(256) void rnn_scan(
    const float* __restrict__ Ua, const float* __restrict__ Ub, const float* __restrict__ Wh,
    const float* __restrict__ ba, const float* __restrict__ bb, const float* __restrict__ bv,
    const ushort_t* __restrict__ P,     // 32768x3072 bf16
    ushort_t* __restrict__ hbuf,        // 2 x 32 x 1024 bf16 (double-buffered broadcast)
    unsigned int* __restrict__ arr,     // 2 x 1024 per-step barrier counters
    float* __restrict__ out) {

    __shared__ ushort_t Hs[16 * DD];          // 32KB staged h (swizzled)
    __shared__ float Red[4][3][16][16];       // 12KB K-split partials

    int g = blockIdx.x;
    int slice = g & 63, bg = g >> 6;
    int e0 = slice * 16;
    int tid = threadIdx.x, lane = tid & 63, wv = tid >> 6;
    int l15 = lane & 15, q = lane >> 4;

    // ---- preload recurrent weight fragments into registers (96 VGPR/lane)
    bf16x8 wf[3][8];
#pragma unroll
    for (int nt = 0; nt < 3; nt++) {
        const float* Um = (nt == 0) ? Ua : (nt == 1) ? Ub : Wh;
#pragma unroll
        for (int ks = 0; ks < 8; ks++) {
            int e = e0 + l15;
            int d = wv * 256 + ks * 32 + q * 8;
            const float* p = Um + (size_t)e * DD + d;
            us8 u;
#pragma unroll
            for (int j = 0; j < 8; j++) u[j] = f2bf(p[j]);
            wf[nt][ks] = __builtin_bit_cast(bf16x8, u);
        }
    }

    // ---- per-thread ownership for the elementwise epilogue: thread = (batch, dim)
    int bcomb = tid >> 4;            // 0..15 batch-local
    int ncomb = tid & 15;            // 0..15 dim-local
    int bglob = bg * 16 + bcomb;
    int ecomb = e0 + ncomb;
    float bias_a = ba[ecomb], bias_b = bb[ecomb], bias_v = bv[ecomb];
    float hreg = 0.f;                // fp32 master h state lives here across all steps
    int hoff = bglob * DD + ecomb;

    const ushort_t* hsrc_base = hbuf + bg * 16 * DD;
    unsigned int* myarr = arr + bg * TT;

    for (int t = 0; t < TT; t++) {
        // prefetch the x-projection values (independent of h -> issue early)
        const ushort_t* pp = P + ((size_t)t * BB + bglob) * GN + ecomb;
        unsigned short pax = pp[0];
        unsigned short pbx = pp[DD];
        unsigned short pwx = pp[2 * DD];

        // stage h (16 batches x 1024 d, bf16) into swizzled LDS
        const ushort_t* hsrc = hsrc_base + (t & 1) * (BB * DD);
#pragma unroll
        for (int p2 = 0; p2 < 8; p2++) {
            int chunk = p2 * 256 + tid;        // 0..2047 16B chunks
            int m = chunk >> 7, c = chunk & 127;
            uint4 v = *(const uint4*)(hsrc + m * DD + c * 8);
            int csw = (c & ~7) | ((c & 7) ^ (m & 7));
            *(uint4*)&Hs[m * DD + csw * 8] = v;
        }
        __syncthreads();

        // MFMA: each wave does its K-quarter for all 3 matrices
        f32x4 a0 = {0.f,0.f,0.f,0.f}, a1 = {0.f,0.f,0.f,0.f}, a2 = {0.f,0.f,0.f,0.f};
#pragma unroll
        for (int ks = 0; ks < 8; ks++) {
            int c = wv * 32 + ks * 4 + q;
            int csw = (c & ~7) | ((c & 7) ^ (l15 & 7));
            bf16x8 af = *(const bf16x8*)&Hs[l15 * DD + csw * 8];
            a0 = __builtin_amdgcn_mfma_f32_16x16x32_bf16(af, wf[0][ks], a0, 0, 0, 0);
            a1 = __builtin_amdgcn_mfma_f32_16x16x32_bf16(af, wf[1][ks], a1, 0, 0, 0);
            a2 = __builtin_amdgcn_mfma_f32_16x16x32_bf16(af, wf[2][ks], a2, 0, 0, 0);
        }
#pragma unroll
        for (int i = 0; i < 4; i++) {
            Red[wv][0][q * 4 + i][l15] = a0[i];
            Red[wv][1][q * 4 + i][l15] = a1[i];
            Red[wv][2][q * 4 + i][l15] = a2[i];
        }
        __syncthreads();

        // combine: K-reduce across waves, gates, h update, outputs
        float pa = 0.f, pb = 0.f, pv = 0.f;
#pragma unroll
        for (int w = 0; w < 4; w++) {
            pa += Red[w][0][bcomb][ncomb];
            pb += Red[w][1][bcomb][ncomb];
            pv += Red[w][2][bcomb][ncomb];
        }
        float aval = pa + bf2f(pax) + bias_a;
        float bval = pb + bf2f(pbx) + bias_b;
        float vval = pv + bf2f(pwx) + bias_v;
        float alpha = 1.f / (1.f + __expf(-aval));
        float beta  = 1.f / (1.f + __expf(-bval));
        float vtan  = tanhf(vval);
        float hn = alpha * hreg + beta * vtan;
        hreg = hn;
        hbuf[((t + 1) & 1) * (BB * DD) + hoff] = f2bf(hn);
        out[(size_t)(TT + 1 + t) * (BB * DD) + hoff] = hn;               // h[t+1]
        float sg = 1.f / (1.f + __expf(-hn));
        out[(size_t)t * (BB * DD) + hoff] = hn * hn * sg;                // h*silu(h)

        // 64-WG group barrier (per-step counter, release/acquire at agent scope)
        if (t < TT - 1) {
            __syncthreads();
            if (tid == 0) {
                __hip_atomic_fetch_add(&myarr[t], 1u, __ATOMIC_RELEASE, __HIP_MEMORY_SCOPE_AGENT);
                while (__hip_atomic_load(&myarr[t], __ATOMIC_ACQUIRE, __HIP_MEMORY_SCOPE_AGENT) < 64u) {
                    __builtin_amdgcn_s_sleep(1);
                }
            }
            __syncthreads();
        }
    }
}

// ---------------------------------------------------------------- launch
extern "C" void kernel_launch(void* const* d_in, const int* in_sizes, int n_in,
                              void* d_out, int out_size, void* d_ws, size_t ws_size,
                              hipStream_t stream) {
    const float* x   = (const float*)d_in[0];
    const float* Wa  = (const float*)d_in[1];
    const float* Uaw = (const float*)d_in[2];
    const float* bal = (const float*)d_in[3];
    const float* Wb  = (const float*)d_in[4];
    const float* Ubw = (const float*)d_in[5];
    const float* bbe = (const float*)d_in[6];
    const float* Whw = (const float*)d_in[7];
    const float* Wx  = (const float*)d_in[8];
    const float* bw  = (const float*)d_in[9];
    float* out = (float*)d_out;

    // ws layout (262.1 MiB total):
    char* ws = (char*)d_ws;
    ushort_t* P    = (ushort_t*)ws;                                   // 201326592 B
    ushort_t* xbf  = (ushort_t*)(ws + 201326592);                     //  67108864 B
    ushort_t* Wcat = (ushort_t*)(ws + 201326592 + 67108864);          //   6291456 B
    ushort_t* hbuf = (ushort_t*)(ws + 274726912);                     //    131072 B
    unsigned int* arr = (unsigned int*)(ws + 274726912 + 131072);     //      8192 B

    hipMemsetAsync(hbuf, 0, 131072 + 8192, stream);                       // h0 + barrier counters
    hipMemsetAsync(out + (size_t)TT * (BB * DD), 0, (BB * DD) * sizeof(float), stream);  // h[0] output

    cvt_f32_bf16<<<512, 256, 0, stream>>>((const float4*)x,  (ushort4*)xbf,  (GM * GK) / 4);
    cvt_f32_bf16<<<64, 256, 0, stream>>>((const float4*)Wa, (ushort4*)Wcat, (DD * DD) / 4);
    cvt_f32_bf16<<<64, 256, 0, stream>>>((const float4*)Wb, (ushort4*)(Wcat + DD * DD), (DD * DD) / 4);
    cvt_f32_bf16<<<64, 256, 0, stream>>>((const float4*)Wx, (ushort4*)(Wcat + 2 * DD * DD), (DD * DD) / 4);

    gemm_xproj<<<(GM / 128) * (GN / 128), 256, 0, stream>>>(xbf, Wcat, P);

    rnn_scan<<<128, 256, 0, stream>>>(Uaw, Ubw, Whw, bal, bbe, bw, P, hbuf, arr, out);
}

// Round 2
// 7183.283 us; speedup vs baseline: 1.0976x; 1.0976x over previous
//
#include <hip/hip_runtime.h>
#include <stdint.h>

// Round 2: remove agent-scope release/acquire fences from the per-step barrier.
// h broadcast + barrier counters now use RELAXED agent-scope atomics (sc1, LLC-coherent,
// no buffer_wbl2 / buffer_inv L2 maintenance). Ordering producer-side via explicit
// per-wave s_waitcnt vmcnt(0) + __syncthreads before the counter increment.

#define TT 1024
#define BB 32
#define DD 1024
#define GM (TT * BB)   // 32768
#define GN 3072
#define GK 1024

typedef __attribute__((ext_vector_type(8))) __bf16 bf16x8;
typedef __attribute__((ext_vector_type(8))) unsigned short us8;
typedef __attribute__((ext_vector_type(4))) float f32x4;
typedef unsigned short ushort_t;
typedef unsigned long long ull_t;

__device__ __forceinline__ unsigned short f2bf(float f) {
    unsigned u = __builtin_bit_cast(unsigned, f);
    return (unsigned short)((u + 0x8000u) >> 16);  // round-half-up; inputs are finite
}
__device__ __forceinline__ float bf2f(unsigned short h) {
    unsigned u = ((unsigned)h) << 16;
    return __builtin_bit_cast(float, u);
}

// ---------------------------------------------------------------- cvt fp32->bf16
__global__ __launch_bounds__(256) void cvt_f32_bf16(const float4* __restrict__ src,
                                                    ushort4* __restrict__ dst, int n4) {
    int i = blockIdx.x * 256 + threadIdx.x;
    int stride = gridDim.x * 256;
    for (; i < n4; i += stride) {
        float4 v = src[i];
        ushort4 o;
        o.x = f2bf(v.x); o.y = f2bf(v.y); o.z = f2bf(v.z); o.w = f2bf(v.w);
        dst[i] = o;
    }
}

// ---------------------------------------------------------------- GEMM: P = Xbf @ Wcat^T
// 128x128 tile, BK=64, 4 waves in 2x2, XOR-swizzled LDS (16B chunk ^ (row&7)) -> 2-way (free).
#define SUPER 16
__global__ __launch_bounds__(256) void gemm_xproj(const ushort_t* __restrict__ A,   // 32768x1024 bf16
                                                  const ushort_t* __restrict__ Bw,  // 3072x1024 bf16
                                                  ushort_t* __restrict__ P) {       // 32768x3072 bf16
    __shared__ ushort_t As[128 * 64];
    __shared__ ushort_t Bs[128 * 64];

    int bid = blockIdx.x;
    int st = bid / (SUPER * 24);
    int r  = bid % (SUPER * 24);
    int tm = st * SUPER + (r & (SUPER - 1));   // supertile order: 16 M-tiles share A in L2/LLC
    int tn = r / SUPER;

    int tid = threadIdx.x;
    int lane = tid & 63, wv = tid >> 6;
    int wm = wv >> 1, wn = wv & 1;
    int l15 = lane & 15, q = lane >> 4;

    f32x4 acc[4][4];
#pragma unroll
    for (int mi = 0; mi < 4; mi++)
#pragma unroll
        for (int ni = 0; ni < 4; ni++) acc[mi][ni] = (f32x4){0.f, 0.f, 0.f, 0.f};

    const ushort_t* Abase = A + (size_t)(tm * 128) * GK;
    const ushort_t* Bbase = Bw + (size_t)(tn * 128) * GK;
    int c8 = tid & 7, rr = tid >> 3;  // rr: 0..31

    for (int kit = 0; kit < 16; kit++) {
        int k0 = kit * 64;
        if (kit) __syncthreads();
#pragma unroll
        for (int p = 0; p < 4; p++) {
            int row = p * 32 + rr;
            int sw = c8 ^ (row & 7);
            uint4 va = *(const uint4*)(Abase + (size_t)row * GK + k0 + c8 * 8);
            *(uint4*)&As[row * 64 + sw * 8] = va;
            uint4 vb = *(const uint4*)(Bbase + (size_t)row * GK + k0 + c8 * 8);
            *(uint4*)&Bs[row * 64 + sw * 8] = vb;
        }
        __syncthreads();
#pragma unroll
        for (int ks = 0; ks < 2; ks++) {
            bf16x8 af[4], bfr[4];
#pragma unroll
            for (int mi = 0; mi < 4; mi++) {
                int rl = wm * 64 + mi * 16 + l15;
                int sw = (ks * 4 + q) ^ (rl & 7);
                af[mi] = *(const bf16x8*)&As[rl * 64 + sw * 8];
            }
#pragma unroll
            for (int ni = 0; ni < 4; ni++) {
                int rl = wn * 64 + ni * 16 + l15;
                int sw = (ks * 4 + q) ^ (rl & 7);
                bfr[ni] = *(const bf16x8*)&Bs[rl * 64 + sw * 8];
            }
#pragma unroll
            for (int mi = 0; mi < 4; mi++)
#pragma unroll
                for (int ni = 0; ni < 4; ni++)
                    acc[mi][ni] = __builtin_amdgcn_mfma_f32_16x16x32_bf16(af[mi], bfr[ni], acc[mi][ni], 0, 0, 0);
        }
    }
    // epilogue: C/D layout col=lane&15, row=(lane>>4)*4+reg  [verified m89/m91]
#pragma unroll
    for (int mi = 0; mi < 4; mi++)
#pragma unroll
        for (int ni = 0; ni < 4; ni++) {
            int n = tn * 128 + wn * 64 + ni * 16 + l15;
#pragma unroll
            for (int i = 0; i < 4; i++) {
                int m = tm * 128 + wm * 64 + mi * 16 + q * 4 + i;
                P[(size_t)m * GN + n] = f2bf(acc[mi][ni][i]);
            }
        }
}

// ---------------------------------------------------------------- persistent RNN scan
// 128 WGs: bg = blockIdx>>6 (16 batches), slice = blockIdx&63 (16 dims).
// Weights as B-frags in registers: wf[mat][ks], wave wv covers k in [wv*256, wv*256+256).
// Cross-WG h handoff: relaxed agent-scope 8B atomics (LLC-coherent, no cache fences).
__global__ __launch_bounds__(256) void rnn_scan(
    const float* __restrict__ Ua, const float* __restrict__ Ub, const float* __restrict__ Wh,
    const float* __restrict__ ba, const float* __restrict__ bb, const float* __restrict__ bv,
    const ushort_t* __restrict__ P,     // 32768x3072 bf16
    ushort_t* __restrict__ hbuf,        // 2 x 32 x 1024 bf16 (double-buffered broadcast)
    unsigned int* __restrict__ arr,     // 2 x 1024 per-step barrier counters
    float* __restrict__ out) {

    __shared__ ushort_t Hs[16 * DD];                  // 32KB staged h (swizzled)
    __shared__ float Red[4][3][16][16];               // 12KB K-split partials
    __shared__ __align__(16) ushort_t Hloc[16][16];   // 512B h repack for 8B stores

    int g = blockIdx.x;
    int slice = g & 63, bg = g >> 6;
    int e0 = slice * 16;
    int tid = threadIdx.x, lane = tid & 63, wv = tid >> 6;
    int l15 = lane & 15, q = lane >> 4;

    // ---- preload recurrent weight fragments into registers (96 VGPR/lane)
    bf16x8 wf[3][8];
#pragma unroll
    for (int nt = 0; nt < 3; nt++) {
        const float* Um = (nt == 0) ? Ua : (nt == 1) ? Ub : Wh;
#pragma unroll
        for (int ks = 0; ks < 8; ks++) {
            int e = e0 + l15;
            int d = wv * 256 + ks * 32 + q * 8;
            const float* p = Um + (size_t)e * DD + d;
            us8 u;
#pragma unroll
            for (int j = 0; j < 8; j++) u[j] = f2bf(p[j]);
            wf[nt][ks] = __builtin_bit_cast(bf16x8, u);
        }
    }

    // ---- per-thread ownership for the elementwise epilogue: thread = (batch, dim)
    int bcomb = tid >> 4;            // 0..15 batch-local
    int ncomb = tid & 15;            // 0..15 dim-local
    int bglob = bg * 16 + bcomb;
    int ecomb = e0 + ncomb;
    float bias_a = ba[ecomb], bias_b = bb[ecomb], bias_v = bv[ecomb];
    float hreg = 0.f;                // fp32 master h state lives here across all steps
    int hoff = bglob * DD + ecomb;

    // h store lane mapping (wave 0 only): batch b = tid>>2, dim-quad c4 = tid&3
    int sb = tid >> 2, sc4 = tid & 3;

    unsigned int* myarr = arr + bg * TT;

    for (int t = 0; t < TT; t++) {
        // prefetch the x-projection values (independent of h -> issue early)
        const ushort_t* pp = P + ((size_t)t * BB + bglob) * GN + ecomb;
        unsigned short pax = pp[0];
        unsigned short pbx = pp[DD];
        unsigned short pwx = pp[2 * DD];

        // stage h (16 batches x 1024 d, bf16) into swizzled LDS via 8B LLC-coherent loads
        const ushort_t* hsrc = hbuf + (t & 1) * (BB * DD) + bg * 16 * DD;
#pragma unroll
        for (int m = 0; m < 16; m++) {
            ull_t v = __hip_atomic_load((const ull_t*)(hsrc + m * DD + tid * 4),
                                        __ATOMIC_RELAXED, __HIP_MEMORY_SCOPE_AGENT);
            int cc = tid >> 1, half = tid & 1;                 // 16B chunk / 8B half
            int ccsw = (cc & ~7) | ((cc & 7) ^ (m & 7));
            *(ull_t*)&Hs[m * DD + ccsw * 8 + half * 4] = v;
        }
        __syncthreads();

        // MFMA: each wave does its K-quarter for all 3 matrices
        f32x4 a0 = {0.f,0.f,0.f,0.f}, a1 = {0.f,0.f,0.f,0.f}, a2 = {0.f,0.f,0.f,0.f};
#pragma unroll
        for (int ks = 0; ks < 8; ks++) {
            int c = wv * 32 + ks * 4 + q;
            int csw = (c & ~7) | ((c & 7) ^ (l15 & 7));
            bf16x8 af = *(const bf16x8*)&Hs[l15 * DD + csw * 8];
            a0 = __builtin_amdgcn_mfma_f32_16x16x32_bf16(af, wf[0][ks], a0, 0, 0, 0);
            a1 = __builtin_amdgcn_mfma_f32_16x16x32_bf16(af, wf[1][ks], a1, 0, 0, 0);
            a2 = __builtin_amdgcn_mfma_f32_16x16x32_bf16(af, wf[2][ks], a2, 0, 0, 0);
        }
#pragma unroll
        for (int i = 0; i < 4; i++) {
            Red[wv][0][q * 4 + i][l15] = a0[i];
            Red[wv][1][q * 4 + i][l15] = a1[i];
            Red[wv][2][q * 4 + i][l15] = a2[i];
        }
        __syncthreads();

        // combine: K-reduce across waves, gates, h update, outputs
        float pa = 0.f, pb = 0.f, pv = 0.f;
#pragma unroll
        for (int w = 0; w < 4; w++) {
            pa += Red[w][0][bcomb][ncomb];
            pb += Red[w][1][bcomb][ncomb];
            pv += Red[w][2][bcomb][ncomb];
        }
        float aval = pa + bf2f(pax) + bias_a;
        float bval = pb + bf2f(pbx) + bias_b;
        float vval = pv + bf2f(pwx) + bias_v;
        float alpha = 1.f / (1.f + __expf(-aval));
        float beta  = 1.f / (1.f + __expf(-bval));
        float vtan  = tanhf(vval);
        float hn = alpha * hreg + beta * vtan;
        hreg = hn;
        out[(size_t)(TT + 1 + t) * (BB * DD) + hoff] = hn;               // h[t+1]
        float sg = 1.f / (1.f + __expf(-hn));
        out[(size_t)t * (BB * DD) + hoff] = hn * hn * sg;                // h*silu(h)
        Hloc[bcomb][ncomb] = f2bf(hn);                                   // repack for 8B stores

        if (t < TT - 1) {
            __syncthreads();                          // Hloc ready
            if (tid < 64) {                           // wave 0: 8B LLC-coherent h stores
                ull_t v = *(const ull_t*)&Hloc[sb][sc4 * 4];
                ushort_t* hnext = hbuf + ((t + 1) & 1) * (BB * DD);
                __hip_atomic_store((ull_t*)(hnext + (bg * 16 + sb) * DD + e0 + sc4 * 4), v,
                                   __ATOMIC_RELAXED, __HIP_MEMORY_SCOPE_AGENT);
            }
            // every wave drains its own vmem (h stores reached LLC) before signaling
            asm volatile("s_waitcnt vmcnt(0)" ::: "memory");
            __syncthreads();
            if (tid == 0) {
                __hip_atomic_fetch_add(&myarr[t], 1u, __ATOMIC_RELAXED, __HIP_MEMORY_SCOPE_AGENT);
                while (__hip_atomic_load(&myarr[t], __ATOMIC_RELAXED, __HIP_MEMORY_SCOPE_AGENT) < 64u) {
                    __builtin_amdgcn_s_sleep(1);
                }
            }
            __syncthreads();
        }
    }
}

// ---------------------------------------------------------------- launch
extern "C" void kernel_launch(void* const* d_in, const int* in_sizes, int n_in,
                              void* d_out, int out_size, void* d_ws, size_t ws_size,
                              hipStream_t stream) {
    const float* x   = (const float*)d_in[0];
    const float* Wa  = (const float*)d_in[1];
    const float* Uaw = (const float*)d_in[2];
    const float* bal = (const float*)d_in[3];
    const float* Wb  = (const float*)d_in[4];
    const float* Ubw = (const float*)d_in[5];
    const float* bbe = (const float*)d_in[6];
    const float* Whw = (const float*)d_in[7];
    const float* Wx  = (const float*)d_in[8];
    const float* bw  = (const float*)d_in[9];
    float* out = (float*)d_out;

    // ws layout (262.1 MiB total):
    char* ws = (char*)d_ws;
    ushort_t* P    = (ushort_t*)ws;                                   // 201326592 B
    ushort_t* xbf  = (ushort_t*)(ws + 201326592);                     //  67108864 B
    ushort_t* Wcat = (ushort_t*)(ws + 201326592 + 67108864);          //   6291456 B
    ushort_t* hbuf = (ushort_t*)(ws + 274726912);                     //    131072 B
    unsigned int* arr = (unsigned int*)(ws + 274726912 + 131072);     //      8192 B

    hipMemsetAsync(hbuf, 0, 131072 + 8192, stream);                       // h0 + barrier counters
    hipMemsetAsync(out + (size_t)TT * (BB * DD), 0, (BB * DD) * sizeof(float), stream);  // h[0] output

    cvt_f32_bf16<<<512, 256, 0, stream>>>((const float4*)x,  (ushort4*)xbf,  (GM * GK) / 4);
    cvt_f32_bf16<<<64, 256, 0, stream>>>((const float4*)Wa, (ushort4*)Wcat, (DD * DD) / 4);
    cvt_f32_bf16<<<64, 256, 0, stream>>>((const float4*)Wb, (ushort4*)(Wcat + DD * DD), (DD * DD) / 4);
    cvt_f32_bf16<<<64, 256, 0, stream>>>((const float4*)Wx, (ushort4*)(Wcat + 2 * DD * DD), (DD * DD) / 4);

    gemm_xproj<<<(GM / 128) * (GN / 128), 256, 0, stream>>>(xbf, Wcat, P);

    rnn_scan<<<128, 256, 0, stream>>>(Uaw, Ubw, Whw, bal, bbe, bw, P, hbuf, arr, out);
}